// Round 10
// baseline (20391.200 us; speedup 1.0000x reference)
//
#include <hip/hip_runtime.h>
#include <stdint.h>

#define LAYERS    5
#define INPUT_DIM 512
#define CODE_DIM  2048
#define BATCH     32768
#define KSP       32

#define BM  128
#define BN  128
#define BKT 16

// ---------------------------------------------------------------------------
// D [512][2048] -> Dt [2048][512]  (bit copy)
__global__ __launch_bounds__(256) void transpose_512x2048_kernel(const float* __restrict__ src,
                                                                 float* __restrict__ dst)
{
    __shared__ float tile[32][33];
    const int tx = threadIdx.x;
    const int ty = threadIdx.y;
    const int cb = blockIdx.x * 32;
    const int ib = blockIdx.y * 32;
    #pragma unroll
    for (int j = 0; j < 32; j += 8)
        tile[ty + j][tx] = src[(size_t)(ib + ty + j) * CODE_DIM + cb + tx];
    __syncthreads();
    #pragma unroll
    for (int j = 0; j < 32; j += 8)
        dst[(size_t)(cb + ty + j) * INPUT_DIM + ib + tx] = tile[tx][ty + j];
}

// ---------------------------------------------------------------------------
// u = x@Wl (+ z@Sl for l>0).  Arithmetic contract (np/BLAS-faithful):
//  - x@W: one f32 accumulator per element, k = 0..511 strictly ascending fmaf
//  - z@S: separate zero-init accumulator, 32 nz folded ascending-index, fmaf
//  - u = xw + zs (single add)
// r8 structure (8x8/thread, 92 VGPR, conflict-free B reads) + DOUBLE-BUFFERED
// LDS: next tile's global loads issued BEFORE compute (latency hides under
// fmaf), ds_write after, ONE barrier per tile.  Static buffer indices via
// 2-tile unroll (rule #20: no runtime-indexed register arrays).
__global__ __launch_bounds__(256) void gemm_layer_kernel(
    const float* __restrict__ x, const float* __restrict__ Wl,
    const float* __restrict__ Sl, const int* __restrict__ zidx,
    const float* __restrict__ zval, float* __restrict__ u)
{
    __shared__ float As[2][BKT][BM + 4];   // transposed: As[b][k][m]
    __shared__ float Bs[2][BKT][BN + 4];

    const int t   = threadIdx.x;
    const int c0  = blockIdx.x * BN;
    const int r0  = blockIdx.y * BM;
    const int tm0 = (t >> 4) * 8;         // 8 rows
    const int cn  = (t & 15) * 4;         // col quads at cn, cn+64

    // staging-thread geometry (same as r8)
    const int f0 = t * 2,     ar0 = f0 >> 2, akq0 = f0 & 3;
    const int f1 = t * 2 + 1, ar1 = f1 >> 2, akq1 = f1 & 3;
    const int g0 = t * 2,     bkr0 = g0 >> 5, bcq0 = g0 & 31;
    const int g1 = t * 2 + 1, bkr1 = g1 >> 5, bcq1 = g1 & 31;

    float4 ra0, ra1, rb0, rb1;            // in-flight stage registers

    auto load_tile = [&](int kte) {       // kte = element offset of tile
        ra0 = *(const float4*)&x[(size_t)(r0 + ar0) * INPUT_DIM + kte + akq0 * 4];
        ra1 = *(const float4*)&x[(size_t)(r0 + ar1) * INPUT_DIM + kte + akq1 * 4];
        rb0 = *(const float4*)&Wl[(size_t)(kte + bkr0) * CODE_DIM + c0 + bcq0 * 4];
        rb1 = *(const float4*)&Wl[(size_t)(kte + bkr1) * CODE_DIM + c0 + bcq1 * 4];
    };
    auto write_tile = [&](float (*Asb)[BM + 4], float (*Bsb)[BN + 4]) {
        Asb[akq0 * 4 + 0][ar0] = ra0.x;
        Asb[akq0 * 4 + 1][ar0] = ra0.y;
        Asb[akq0 * 4 + 2][ar0] = ra0.z;
        Asb[akq0 * 4 + 3][ar0] = ra0.w;
        Asb[akq1 * 4 + 0][ar1] = ra1.x;
        Asb[akq1 * 4 + 1][ar1] = ra1.y;
        Asb[akq1 * 4 + 2][ar1] = ra1.z;
        Asb[akq1 * 4 + 3][ar1] = ra1.w;
        *(float4*)&Bsb[bkr0][bcq0 * 4] = rb0;
        *(float4*)&Bsb[bkr1][bcq1 * 4] = rb1;
    };

    float acc[8][8];
    #pragma unroll
    for (int i = 0; i < 8; ++i)
        #pragma unroll
        for (int j = 0; j < 8; ++j) acc[i][j] = 0.f;

    auto compute_tile = [&](const float (*Asb)[BM + 4], const float (*Bsb)[BN + 4]) {
        #pragma unroll
        for (int kk = 0; kk < BKT; ++kk) {      // strictly ascending k chain
            float a[8], b[8];
            *(float4*)&a[0] = *(const float4*)&Asb[kk][tm0];
            *(float4*)&a[4] = *(const float4*)&Asb[kk][tm0 + 4];
            *(float4*)&b[0] = *(const float4*)&Bsb[kk][cn];        // conflict-free
            *(float4*)&b[4] = *(const float4*)&Bsb[kk][cn + 64];   // conflict-free
            #pragma unroll
            for (int i = 0; i < 8; ++i)
                #pragma unroll
                for (int j = 0; j < 8; ++j)
                    acc[i][j] = fmaf(a[i], b[j], acc[i][j]);
        }
    };

    // prologue: tile 0 -> buf0
    load_tile(0);
    write_tile(As[0], Bs[0]);
    __syncthreads();

    for (int kt = 0; kt < INPUT_DIM; kt += 2 * BKT) {
        // buf0 holds tile kt
        load_tile(kt + BKT);                   // kt+16 <= 496: always valid
        compute_tile(As[0], Bs[0]);
        write_tile(As[1], Bs[1]);
        __syncthreads();
        if (kt + 2 * BKT < INPUT_DIM) load_tile(kt + 2 * BKT);
        compute_tile(As[1], Bs[1]);
        if (kt + 2 * BKT < INPUT_DIM) write_tile(As[0], Bs[0]);
        __syncthreads();
    }

    if (Sl != nullptr) {
        #pragma unroll
        for (int i = 0; i < 8; ++i) {           // FULLY unrolled: acc[i] static
            const int r = r0 + tm0 + i;
            const int*   ip = zidx + (size_t)r * KSP;   // ascending code index
            const float* vp = zval + (size_t)r * KSP;
            float zacc[8];
            #pragma unroll
            for (int j = 0; j < 8; ++j) zacc[j] = 0.f;
            for (int k = 0; k < KSP; ++k) {     // runtime k only touches memory
                int   j = ip[k];
                float v = vp[k];
                const float* srow = Sl + (size_t)j * CODE_DIM + c0 + cn;
                float4 s0 = *(const float4*)&srow[0];
                float4 s1 = *(const float4*)&srow[64];
                zacc[0] = fmaf(v, s0.x, zacc[0]);
                zacc[1] = fmaf(v, s0.y, zacc[1]);
                zacc[2] = fmaf(v, s0.z, zacc[2]);
                zacc[3] = fmaf(v, s0.w, zacc[3]);
                zacc[4] = fmaf(v, s1.x, zacc[4]);
                zacc[5] = fmaf(v, s1.y, zacc[5]);
                zacc[6] = fmaf(v, s1.z, zacc[6]);
                zacc[7] = fmaf(v, s1.w, zacc[7]);
            }
            #pragma unroll
            for (int j = 0; j < 8; ++j)     // single add: u = xw + zs
                acc[i][j] = acc[i][j] + zacc[j];
        }
    }

    #pragma unroll
    for (int i = 0; i < 8; ++i) {
        float* up = u + (size_t)(r0 + tm0 + i) * CODE_DIM + c0 + cn;
        *(float4*)&up[0]  = make_float4(acc[i][0], acc[i][1], acc[i][2], acc[i][3]);
        *(float4*)&up[64] = make_float4(acc[i][4], acc[i][5], acc[i][6], acc[i][7]);
    }
}

// ---------------------------------------------------------------------------
// top-32 by |u| (desc, tie -> lower index), one WAVE per row, registers only.
// Output written index-sorted.
__global__ __launch_bounds__(256) void topk32_wave_kernel(const float* __restrict__ u,
                                                          int* __restrict__ zidx,
                                                          float* __restrict__ zval)
{
    const int lane = threadIdx.x & 63;
    const int row  = blockIdx.x * 4 + (threadIdx.x >> 6);
    const float* ur = u + (size_t)row * CODE_DIM;

    uint32_t a[32];
    #pragma unroll
    for (int q = 0; q < 8; ++q) {
        float4 v = *(const float4*)&ur[lane * 32 + q * 4];
        a[q * 4 + 0] = __float_as_uint(v.x) & 0x7fffffffu;
        a[q * 4 + 1] = __float_as_uint(v.y) & 0x7fffffffu;
        a[q * 4 + 2] = __float_as_uint(v.z) & 0x7fffffffu;
        a[q * 4 + 3] = __float_as_uint(v.w) & 0x7fffffffu;
    }

    uint32_t bf = 0; int bj = 32;
    #pragma unroll
    for (int j = 0; j < 32; ++j)
        if (bj == 32 || a[j] > bf) { bf = a[j]; bj = j; }

    uint32_t wi = 0xFFFFFFFFu;
    for (int it = 0; it < KSP; ++it) {
        uint32_t cf = bf;
        uint32_t ci = (bj < 32) ? (uint32_t)(lane * 32 + bj) : 0x7FFFFFFFu;
        #pragma unroll
        for (int off = 1; off <= 32; off <<= 1) {
            uint32_t of = __shfl_xor(cf, off);
            uint32_t oi = __shfl_xor(ci, off);
            if (of > cf || (of == cf && oi < ci)) { cf = of; ci = oi; }
        }
        if (lane == it) wi = ci;
        if ((ci >> 5) == (uint32_t)lane) {    // winner rescans strictly below (cf,ci)
            uint32_t nbf = 0; int nbj = 32;
            #pragma unroll
            for (int j = 0; j < 32; ++j) {
                uint32_t gi = (uint32_t)(lane * 32 + j);
                bool less = (a[j] < cf) || (a[j] == cf && gi > ci);
                if (less && (nbj == 32 || a[j] > nbf)) { nbf = a[j]; nbj = j; }
            }
            bf = nbf; bj = nbj;
        }
    }

    int rank = 0;
    #pragma unroll
    for (int m = 0; m < 32; ++m) {
        uint32_t om = __shfl(wi, m);
        rank += (om < wi) ? 1 : 0;
    }
    if (lane < KSP) {
        int idx = (int)wi;
        zidx[(size_t)row * KSP + rank] = idx;
        zval[(size_t)row * KSP + rank] = ur[idx];
    }
}

// ---------------------------------------------------------------------------
__global__ __launch_bounds__(256) void zfill_scatter_kernel(const int* __restrict__ zidx,
                                                            const float* __restrict__ zval,
                                                            float* __restrict__ zden)
{
    const int t  = threadIdx.x;
    const int r0 = blockIdx.x * 8;
    float* base = zden + (size_t)r0 * CODE_DIM;
    const float4 zero = make_float4(0.f, 0.f, 0.f, 0.f);
    for (int q = t; q < 8 * CODE_DIM / 4; q += 256)
        *(float4*)&base[q * 4] = zero;
    __syncthreads();
    const int rl = t >> 5, k = t & 31;
    int   idx = zidx[(size_t)(r0 + rl) * KSP + k];
    float v   = zval[(size_t)(r0 + rl) * KSP + k];
    base[(size_t)rl * CODE_DIM + idx] = v;
}

// ---------------------------------------------------------------------------
// recon: ascending-index fold of 32 nonzeros, f32 fmaf (np z@D.T faithful)
__global__ __launch_bounds__(128) void recon_kernel(const int* __restrict__ zidx,
                                                    const float* __restrict__ zval,
                                                    const float* __restrict__ Dt,
                                                    float* __restrict__ recon)
{
    const int t   = threadIdx.x;
    const int row = blockIdx.x;
    float4 acc = make_float4(0.f, 0.f, 0.f, 0.f);
    const int*   ip = zidx + (size_t)row * KSP;
    const float* vp = zval + (size_t)row * KSP;
    for (int k = 0; k < KSP; ++k) {
        int   j = ip[k];
        float v = vp[k];
        float4 d = *(const float4*)&Dt[(size_t)j * INPUT_DIM + t * 4];
        acc.x = fmaf(v, d.x, acc.x);
        acc.y = fmaf(v, d.y, acc.y);
        acc.z = fmaf(v, d.z, acc.z);
        acc.w = fmaf(v, d.w, acc.w);
    }
    *(float4*)&recon[(size_t)row * INPUT_DIM + t * 4] = acc;
}

// ---------------------------------------------------------------------------
extern "C" void kernel_launch(void* const* d_in, const int* in_sizes, int n_in,
                              void* d_out, int out_size, void* d_ws, size_t ws_size,
                              hipStream_t stream)
{
    const float* x = (const float*)d_in[0];
    const float* W = (const float*)d_in[1];   // [5][512][2048]
    const float* S = (const float*)d_in[2];   // [5][2048][2048]
    const float* D = (const float*)d_in[3];   // [512][2048]

    float* recon = (float*)d_out;
    float* zden  = (float*)d_out + (size_t)BATCH * INPUT_DIM;  // u scratch, then dense z

    int*   zidx = (int*)d_ws;
    float* zval = (float*)((char*)d_ws + (size_t)BATCH * KSP * 4);
    float* Dt   = (float*)((char*)d_ws + (size_t)2 * BATCH * KSP * 4);

    transpose_512x2048_kernel<<<dim3(CODE_DIM / 32, INPUT_DIM / 32), dim3(32, 8), 0, stream>>>(D, Dt);

    for (int l = 0; l < LAYERS; ++l) {
        const float* Wl = W + (size_t)l * INPUT_DIM * CODE_DIM;
        const float* Sl = (l == 0) ? nullptr : S + (size_t)l * CODE_DIM * CODE_DIM;
        gemm_layer_kernel<<<dim3(CODE_DIM / BN, BATCH / BM), 256, 0, stream>>>(
            x, Wl, Sl, (l == 0) ? nullptr : zidx, (l == 0) ? nullptr : zval, zden);
        topk32_wave_kernel<<<BATCH / 4, 256, 0, stream>>>(zden, zidx, zval);
    }

    zfill_scatter_kernel<<<BATCH / 8, 256, 0, stream>>>(zidx, zval, zden);
    recon_kernel<<<BATCH, 128, 0, stream>>>(zidx, zval, Dt, recon);
}

// Round 11
// 8660.360 us; speedup vs baseline: 2.3545x; 2.3545x over previous
//
#include <hip/hip_runtime.h>
#include <stdint.h>

#define LAYERS    5
#define INPUT_DIM 512
#define CODE_DIM  2048
#define BATCH     32768
#define KSP       32

#define BM  128
#define BN  128
#define BKT 32

#define GLOAD_LDS16(dst, src) \
    __builtin_amdgcn_global_load_lds((const __attribute__((address_space(1))) uint32_t*)(src), \
                                     (__attribute__((address_space(3))) uint32_t*)(dst), 16, 0, 0)

// ---------------------------------------------------------------------------
// D [512][2048] -> Dt [2048][512]  (bit copy)
__global__ __launch_bounds__(256) void transpose_512x2048_kernel(const float* __restrict__ src,
                                                                 float* __restrict__ dst)
{
    __shared__ float tile[32][33];
    const int tx = threadIdx.x;
    const int ty = threadIdx.y;
    const int cb = blockIdx.x * 32;
    const int ib = blockIdx.y * 32;
    #pragma unroll
    for (int j = 0; j < 32; j += 8)
        tile[ty + j][tx] = src[(size_t)(ib + ty + j) * CODE_DIM + cb + tx];
    __syncthreads();
    #pragma unroll
    for (int j = 0; j < 32; j += 8)
        dst[(size_t)(cb + ty + j) * INPUT_DIM + ib + tx] = tile[tx][ty + j];
}

// ---------------------------------------------------------------------------
// u = x@Wl (+ z@Sl for l>0).  Arithmetic contract (np/BLAS-faithful):
//  - x@W: one f32 accumulator per element, k = 0..511 strictly ascending fmaf
//  - z@S: separate zero-init accumulator, 32 nz folded ascending-index, fmaf
//  - u = xw + zs (single add)
// r8 schedule (stage -> barrier -> unrolled compute -> barrier) with:
//  - BKT=32: halves barrier count, 2048 fmaf-cy/wave per tile amortizes it
//  - B staged via global_load_lds (1 KB/wave-instr, 2 rows each; Bs UNPADDED
//    so the wave-linear dest is contiguous; reads stay 2-lanes/bank = free)
// RULES (r5/r6/r7/r10 lessons): acc/zacc only compile-time-indexed (full
// unroll), no lambdas holding regs across compute, no waves_per_eu, 8x8 max.
__global__ __launch_bounds__(256) void gemm_layer_kernel(
    const float* __restrict__ x, const float* __restrict__ Wl,
    const float* __restrict__ Sl, const int* __restrict__ zidx,
    const float* __restrict__ zval, float* __restrict__ u)
{
    __shared__ float As[BKT][BM + 4];   // transposed: As[k][m]; reads broadcast
    __shared__ float Bs[BKT][BN];       // linear rows (gload dest), reads conflict-free

    const int t    = threadIdx.x;
    const int lane = t & 63;
    const int wid  = t >> 6;
    const int c0   = blockIdx.x * BN;
    const int r0   = blockIdx.y * BM;
    const int tm0  = (t >> 4) * 8;        // 8 rows
    const int cn   = (t & 15) * 4;        // col quads at cn, cn+64

    float acc[8][8];
    #pragma unroll
    for (int i = 0; i < 8; ++i)
        #pragma unroll
        for (int j = 0; j < 8; ++j) acc[i][j] = 0.f;

    for (int kt = 0; kt < INPUT_DIM; kt += BKT) {
        // --- stage A: 128 rows x 32 k, transposed into As[k][m] (manual) ---
        #pragma unroll
        for (int i = 0; i < 4; ++i) {
            int f   = t * 4 + i;          // 0..1023 float4s
            int row = f >> 3, kq = f & 7;
            float4 v = *(const float4*)&x[(size_t)(r0 + row) * INPUT_DIM + kt + kq * 4];
            As[kq * 4 + 0][row] = v.x;
            As[kq * 4 + 1][row] = v.y;
            As[kq * 4 + 2][row] = v.z;
            As[kq * 4 + 3][row] = v.w;
        }
        // --- stage B: 32 rows x 128 cols via global_load_lds (2 rows/instr) ---
        #pragma unroll
        for (int s = 0; s < 4; ++s) {
            int r = wid * 8 + s * 2;      // this wave's rows r, r+1
            GLOAD_LDS16(&Bs[r][0],
                        Wl + (size_t)(kt + r + (lane >> 5)) * CODE_DIM + c0 + (lane & 31) * 4);
        }
        __syncthreads();   // drains vmcnt+lgkmcnt (compiler-inserted) before use

        #pragma unroll
        for (int kk = 0; kk < BKT; ++kk) {      // strictly ascending k chain
            float a[8], b[8];
            *(float4*)&a[0] = *(const float4*)&As[kk][tm0];
            *(float4*)&a[4] = *(const float4*)&As[kk][tm0 + 4];
            *(float4*)&b[0] = *(const float4*)&Bs[kk][cn];        // conflict-free
            *(float4*)&b[4] = *(const float4*)&Bs[kk][cn + 64];   // conflict-free
            #pragma unroll
            for (int i = 0; i < 8; ++i)
                #pragma unroll
                for (int j = 0; j < 8; ++j)
                    acc[i][j] = fmaf(a[i], b[j], acc[i][j]);
        }
        __syncthreads();   // tile consumed before next overwrite
    }

    if (Sl != nullptr) {
        #pragma unroll
        for (int i = 0; i < 8; ++i) {           // FULLY unrolled: acc[i] static
            const int r = r0 + tm0 + i;
            const int*   ip = zidx + (size_t)r * KSP;   // ascending code index
            const float* vp = zval + (size_t)r * KSP;
            float zacc[8];
            #pragma unroll
            for (int j = 0; j < 8; ++j) zacc[j] = 0.f;
            for (int k = 0; k < KSP; ++k) {     // runtime k only touches memory
                int   j = ip[k];
                float v = vp[k];
                const float* srow = Sl + (size_t)j * CODE_DIM + c0 + cn;
                float4 s0 = *(const float4*)&srow[0];
                float4 s1 = *(const float4*)&srow[64];
                zacc[0] = fmaf(v, s0.x, zacc[0]);
                zacc[1] = fmaf(v, s0.y, zacc[1]);
                zacc[2] = fmaf(v, s0.z, zacc[2]);
                zacc[3] = fmaf(v, s0.w, zacc[3]);
                zacc[4] = fmaf(v, s1.x, zacc[4]);
                zacc[5] = fmaf(v, s1.y, zacc[5]);
                zacc[6] = fmaf(v, s1.z, zacc[6]);
                zacc[7] = fmaf(v, s1.w, zacc[7]);
            }
            #pragma unroll
            for (int j = 0; j < 8; ++j)     // single add: u = xw + zs
                acc[i][j] = acc[i][j] + zacc[j];
        }
    }

    #pragma unroll
    for (int i = 0; i < 8; ++i) {
        float* up = u + (size_t)(r0 + tm0 + i) * CODE_DIM + c0 + cn;
        *(float4*)&up[0]  = make_float4(acc[i][0], acc[i][1], acc[i][2], acc[i][3]);
        *(float4*)&up[64] = make_float4(acc[i][4], acc[i][5], acc[i][6], acc[i][7]);
    }
}

// ---------------------------------------------------------------------------
// top-32 by |u| (desc, tie -> lower index), one WAVE per row, registers only.
// Output written index-sorted.
__global__ __launch_bounds__(256) void topk32_wave_kernel(const float* __restrict__ u,
                                                          int* __restrict__ zidx,
                                                          float* __restrict__ zval)
{
    const int lane = threadIdx.x & 63;
    const int row  = blockIdx.x * 4 + (threadIdx.x >> 6);
    const float* ur = u + (size_t)row * CODE_DIM;

    uint32_t a[32];
    #pragma unroll
    for (int q = 0; q < 8; ++q) {
        float4 v = *(const float4*)&ur[lane * 32 + q * 4];
        a[q * 4 + 0] = __float_as_uint(v.x) & 0x7fffffffu;
        a[q * 4 + 1] = __float_as_uint(v.y) & 0x7fffffffu;
        a[q * 4 + 2] = __float_as_uint(v.z) & 0x7fffffffu;
        a[q * 4 + 3] = __float_as_uint(v.w) & 0x7fffffffu;
    }

    uint32_t bf = 0; int bj = 32;
    #pragma unroll
    for (int j = 0; j < 32; ++j)
        if (bj == 32 || a[j] > bf) { bf = a[j]; bj = j; }

    uint32_t wi = 0xFFFFFFFFu;
    for (int it = 0; it < KSP; ++it) {
        uint32_t cf = bf;
        uint32_t ci = (bj < 32) ? (uint32_t)(lane * 32 + bj) : 0x7FFFFFFFu;
        #pragma unroll
        for (int off = 1; off <= 32; off <<= 1) {
            uint32_t of = __shfl_xor(cf, off);
            uint32_t oi = __shfl_xor(ci, off);
            if (of > cf || (of == cf && oi < ci)) { cf = of; ci = oi; }
        }
        if (lane == it) wi = ci;
        if ((ci >> 5) == (uint32_t)lane) {    // winner rescans strictly below (cf,ci)
            uint32_t nbf = 0; int nbj = 32;
            #pragma unroll
            for (int j = 0; j < 32; ++j) {
                uint32_t gi = (uint32_t)(lane * 32 + j);
                bool less = (a[j] < cf) || (a[j] == cf && gi > ci);
                if (less && (nbj == 32 || a[j] > nbf)) { nbf = a[j]; nbj = j; }
            }
            bf = nbf; bj = nbj;
        }
    }

    int rank = 0;
    #pragma unroll
    for (int m = 0; m < 32; ++m) {
        uint32_t om = __shfl(wi, m);
        rank += (om < wi) ? 1 : 0;
    }
    if (lane < KSP) {
        int idx = (int)wi;
        zidx[(size_t)row * KSP + rank] = idx;
        zval[(size_t)row * KSP + rank] = ur[idx];
    }
}

// ---------------------------------------------------------------------------
__global__ __launch_bounds__(256) void zfill_scatter_kernel(const int* __restrict__ zidx,
                                                            const float* __restrict__ zval,
                                                            float* __restrict__ zden)
{
    const int t  = threadIdx.x;
    const int r0 = blockIdx.x * 8;
    float* base = zden + (size_t)r0 * CODE_DIM;
    const float4 zero = make_float4(0.f, 0.f, 0.f, 0.f);
    for (int q = t; q < 8 * CODE_DIM / 4; q += 256)
        *(float4*)&base[q * 4] = zero;
    __syncthreads();
    const int rl = t >> 5, k = t & 31;
    int   idx = zidx[(size_t)(r0 + rl) * KSP + k];
    float v   = zval[(size_t)(r0 + rl) * KSP + k];
    base[(size_t)rl * CODE_DIM + idx] = v;
}

// ---------------------------------------------------------------------------
// recon: ascending-index fold of 32 nonzeros, f32 fmaf (np z@D.T faithful)
__global__ __launch_bounds__(128) void recon_kernel(const int* __restrict__ zidx,
                                                    const float* __restrict__ zval,
                                                    const float* __restrict__ Dt,
                                                    float* __restrict__ recon)
{
    const int t   = threadIdx.x;
    const int row = blockIdx.x;
    float4 acc = make_float4(0.f, 0.f, 0.f, 0.f);
    const int*   ip = zidx + (size_t)row * KSP;
    const float* vp = zval + (size_t)row * KSP;
    for (int k = 0; k < KSP; ++k) {
        int   j = ip[k];
        float v = vp[k];
        float4 d = *(const float4*)&Dt[(size_t)j * INPUT_DIM + t * 4];
        acc.x = fmaf(v, d.x, acc.x);
        acc.y = fmaf(v, d.y, acc.y);
        acc.z = fmaf(v, d.z, acc.z);
        acc.w = fmaf(v, d.w, acc.w);
    }
    *(float4*)&recon[(size_t)row * INPUT_DIM + t * 4] = acc;
}

// ---------------------------------------------------------------------------
extern "C" void kernel_launch(void* const* d_in, const int* in_sizes, int n_in,
                              void* d_out, int out_size, void* d_ws, size_t ws_size,
                              hipStream_t stream)
{
    const float* x = (const float*)d_in[0];
    const float* W = (const float*)d_in[1];   // [5][512][2048]
    const float* S = (const float*)d_in[2];   // [5][2048][2048]
    const float* D = (const float*)d_in[3];   // [512][2048]

    float* recon = (float*)d_out;
    float* zden  = (float*)d_out + (size_t)BATCH * INPUT_DIM;  // u scratch, then dense z

    int*   zidx = (int*)d_ws;
    float* zval = (float*)((char*)d_ws + (size_t)BATCH * KSP * 4);
    float* Dt   = (float*)((char*)d_ws + (size_t)2 * BATCH * KSP * 4);

    transpose_512x2048_kernel<<<dim3(CODE_DIM / 32, INPUT_DIM / 32), dim3(32, 8), 0, stream>>>(D, Dt);

    for (int l = 0; l < LAYERS; ++l) {
        const float* Wl = W + (size_t)l * INPUT_DIM * CODE_DIM;
        const float* Sl = (l == 0) ? nullptr : S + (size_t)l * CODE_DIM * CODE_DIM;
        gemm_layer_kernel<<<dim3(CODE_DIM / BN, BATCH / BM), 256, 0, stream>>>(
            x, Wl, Sl, (l == 0) ? nullptr : zidx, (l == 0) ? nullptr : zval, zden);
        topk32_wave_kernel<<<BATCH / 4, 256, 0, stream>>>(zden, zidx, zval);
    }

    zfill_scatter_kernel<<<BATCH / 8, 256, 0, stream>>>(zidx, zval, zden);
    recon_kernel<<<BATCH, 128, 0, stream>>>(zidx, zval, Dt, recon);
}

// Round 12
// 6591.315 us; speedup vs baseline: 3.0936x; 1.3139x over previous
//
#include <hip/hip_runtime.h>
#include <stdint.h>

#define LAYERS    5
#define INPUT_DIM 512
#define CODE_DIM  2048
#define BATCH     32768
#define KSP       32

#define BM  128
#define BN  128
#define BKT 32

#define GLOAD_LDS16(dst, src) \
    __builtin_amdgcn_global_load_lds((const __attribute__((address_space(1))) uint32_t*)(src), \
                                     (__attribute__((address_space(3))) uint32_t*)(dst), 16, 0, 0)

// ---------------------------------------------------------------------------
// D [512][2048] -> Dt [2048][512]  (bit copy)
__global__ __launch_bounds__(256) void transpose_512x2048_kernel(const float* __restrict__ src,
                                                                 float* __restrict__ dst)
{
    __shared__ float tile[32][33];
    const int tx = threadIdx.x;
    const int ty = threadIdx.y;
    const int cb = blockIdx.x * 32;
    const int ib = blockIdx.y * 32;
    #pragma unroll
    for (int j = 0; j < 32; j += 8)
        tile[ty + j][tx] = src[(size_t)(ib + ty + j) * CODE_DIM + cb + tx];
    __syncthreads();
    #pragma unroll
    for (int j = 0; j < 32; j += 8)
        dst[(size_t)(cb + ty + j) * INPUT_DIM + ib + tx] = tile[tx][ty + j];
}

// ---------------------------------------------------------------------------
// u = x@Wl (+ z@Sl for l>0).  Arithmetic contract (np/BLAS-faithful):
//  - x@W: one f32 accumulator per element, k = 0..511 strictly ascending fmaf
//  - z@S: separate zero-init accumulator, 32 nz folded ascending-index, fmaf
//  - u = xw + zs (single add)
// UNCHANGED from r11 (best stable gemm: ~1270 us/layer, 92 VGPR, no spill).
__global__ __launch_bounds__(256) void gemm_layer_kernel(
    const float* __restrict__ x, const float* __restrict__ Wl,
    const float* __restrict__ Sl, const int* __restrict__ zidx,
    const float* __restrict__ zval, float* __restrict__ u)
{
    __shared__ float As[BKT][BM + 4];   // transposed: As[k][m]; reads broadcast
    __shared__ float Bs[BKT][BN];       // linear rows (gload dest), reads conflict-free

    const int t    = threadIdx.x;
    const int lane = t & 63;
    const int wid  = t >> 6;
    const int c0   = blockIdx.x * BN;
    const int r0   = blockIdx.y * BM;
    const int tm0  = (t >> 4) * 8;        // 8 rows
    const int cn   = (t & 15) * 4;        // col quads at cn, cn+64

    float acc[8][8];
    #pragma unroll
    for (int i = 0; i < 8; ++i)
        #pragma unroll
        for (int j = 0; j < 8; ++j) acc[i][j] = 0.f;

    for (int kt = 0; kt < INPUT_DIM; kt += BKT) {
        // --- stage A: 128 rows x 32 k, transposed into As[k][m] (manual) ---
        #pragma unroll
        for (int i = 0; i < 4; ++i) {
            int f   = t * 4 + i;          // 0..1023 float4s
            int row = f >> 3, kq = f & 7;
            float4 v = *(const float4*)&x[(size_t)(r0 + row) * INPUT_DIM + kt + kq * 4];
            As[kq * 4 + 0][row] = v.x;
            As[kq * 4 + 1][row] = v.y;
            As[kq * 4 + 2][row] = v.z;
            As[kq * 4 + 3][row] = v.w;
        }
        // --- stage B: 32 rows x 128 cols via global_load_lds (2 rows/instr) ---
        #pragma unroll
        for (int s = 0; s < 4; ++s) {
            int r = wid * 8 + s * 2;      // this wave's rows r, r+1
            GLOAD_LDS16(&Bs[r][0],
                        Wl + (size_t)(kt + r + (lane >> 5)) * CODE_DIM + c0 + (lane & 31) * 4);
        }
        __syncthreads();   // drains vmcnt+lgkmcnt (compiler-inserted) before use

        #pragma unroll
        for (int kk = 0; kk < BKT; ++kk) {      // strictly ascending k chain
            float a[8], b[8];
            *(float4*)&a[0] = *(const float4*)&As[kk][tm0];
            *(float4*)&a[4] = *(const float4*)&As[kk][tm0 + 4];
            *(float4*)&b[0] = *(const float4*)&Bs[kk][cn];        // conflict-free
            *(float4*)&b[4] = *(const float4*)&Bs[kk][cn + 64];   // conflict-free
            #pragma unroll
            for (int i = 0; i < 8; ++i)
                #pragma unroll
                for (int j = 0; j < 8; ++j)
                    acc[i][j] = fmaf(a[i], b[j], acc[i][j]);
        }
        __syncthreads();   // tile consumed before next overwrite
    }

    if (Sl != nullptr) {
        #pragma unroll
        for (int i = 0; i < 8; ++i) {           // FULLY unrolled: acc[i] static
            const int r = r0 + tm0 + i;
            const int*   ip = zidx + (size_t)r * KSP;   // ascending code index
            const float* vp = zval + (size_t)r * KSP;
            float zacc[8];
            #pragma unroll
            for (int j = 0; j < 8; ++j) zacc[j] = 0.f;
            for (int k = 0; k < KSP; ++k) {     // runtime k only touches memory
                int   j = ip[k];
                float v = vp[k];
                const float* srow = Sl + (size_t)j * CODE_DIM + c0 + cn;
                float4 s0 = *(const float4*)&srow[0];
                float4 s1 = *(const float4*)&srow[64];
                zacc[0] = fmaf(v, s0.x, zacc[0]);
                zacc[1] = fmaf(v, s0.y, zacc[1]);
                zacc[2] = fmaf(v, s0.z, zacc[2]);
                zacc[3] = fmaf(v, s0.w, zacc[3]);
                zacc[4] = fmaf(v, s1.x, zacc[4]);
                zacc[5] = fmaf(v, s1.y, zacc[5]);
                zacc[6] = fmaf(v, s1.z, zacc[6]);
                zacc[7] = fmaf(v, s1.w, zacc[7]);
            }
            #pragma unroll
            for (int j = 0; j < 8; ++j)     // single add: u = xw + zs
                acc[i][j] = acc[i][j] + zacc[j];
        }
    }

    #pragma unroll
    for (int i = 0; i < 8; ++i) {
        float* up = u + (size_t)(r0 + tm0 + i) * CODE_DIM + c0 + cn;
        *(float4*)&up[0]  = make_float4(acc[i][0], acc[i][1], acc[i][2], acc[i][3]);
        *(float4*)&up[64] = make_float4(acc[i][4], acc[i][5], acc[i][6], acc[i][7]);
    }
}

// ---------------------------------------------------------------------------
// top-32 by |u| (desc, tie -> lower index), one WAVE per row, registers only.
// v2: key-only max tree + ballot owner-select (2.5x less wave work than the
// rescan version).  Keys stored as (|u| bits)+1: monotone (exact same order
// and ties), and 0 becomes a popped-sentinel strictly below all live keys.
// All register arrays statically indexed (rule #20).
__global__ __launch_bounds__(256) void topk32_wave_kernel(const float* __restrict__ u,
                                                          int* __restrict__ zidx,
                                                          float* __restrict__ zval)
{
    const int lane = threadIdx.x & 63;
    const int row  = blockIdx.x * 4 + (threadIdx.x >> 6);
    const float* ur = u + (size_t)row * CODE_DIM;

    uint32_t a[32];                       // lane's keys: global idx = lane*32 + j
    #pragma unroll
    for (int q = 0; q < 8; ++q) {
        float4 v = *(const float4*)&ur[lane * 32 + q * 4];
        a[q * 4 + 0] = (__float_as_uint(v.x) & 0x7fffffffu) + 1u;
        a[q * 4 + 1] = (__float_as_uint(v.y) & 0x7fffffffu) + 1u;
        a[q * 4 + 2] = (__float_as_uint(v.z) & 0x7fffffffu) + 1u;
        a[q * 4 + 3] = (__float_as_uint(v.w) & 0x7fffffffu) + 1u;
    }

    uint32_t wi = 0xFFFFFFFFu;            // slot-it winner gidx (lanes 0..31)
    for (int it = 0; it < KSP; ++it) {
        // local max: pairwise tree, all static indices, single-cycle v_max_u32
        uint32_t t0[16], t1[8], t2[4], t3[2];
        #pragma unroll
        for (int j = 0; j < 16; ++j) t0[j] = a[2*j]  > a[2*j+1]  ? a[2*j]  : a[2*j+1];
        #pragma unroll
        for (int j = 0; j < 8;  ++j) t1[j] = t0[2*j] > t0[2*j+1] ? t0[2*j] : t0[2*j+1];
        #pragma unroll
        for (int j = 0; j < 4;  ++j) t2[j] = t1[2*j] > t1[2*j+1] ? t1[2*j] : t1[2*j+1];
        #pragma unroll
        for (int j = 0; j < 2;  ++j) t3[j] = t2[2*j] > t2[2*j+1] ? t2[2*j] : t2[2*j+1];
        const uint32_t mloc = t3[0] > t3[1] ? t3[0] : t3[1];

        // global max: key-only butterfly
        uint32_t g = mloc;
        #pragma unroll
        for (int off = 1; off <= 32; off <<= 1) {
            uint32_t og = __shfl_xor(g, off);
            g = og > g ? og : g;
        }

        // owner = lowest lane whose local max == g  (lowest gidx tie rule)
        unsigned long long bal = __ballot(mloc == g);
        int owner = __ffsll(bal) - 1;

        // local first-match j (lowest j on within-lane ties); valid in owner
        int bj = 0;
        #pragma unroll
        for (int j = 31; j >= 0; --j)
            if (a[j] == g) bj = j;
        int bjo = __shfl(bj, owner);      // owner is wave-uniform

        uint32_t gidx = (uint32_t)owner * 32u + (uint32_t)bjo;
        if (lane == it) wi = gidx;        // capture slot it

        // owner retires the popped element (static reg indices, predicated)
        if (lane == owner) {
            #pragma unroll
            for (int j = 0; j < 32; ++j)
                if (j == bjo) a[j] = 0u;
        }
    }

    // rank winners by index ascending (all distinct), write index-sorted
    int rank = 0;
    #pragma unroll
    for (int m = 0; m < 32; ++m) {
        uint32_t om = __shfl(wi, m);
        rank += (om < wi) ? 1 : 0;
    }
    if (lane < KSP) {
        int idx = (int)wi;
        zidx[(size_t)row * KSP + rank] = idx;
        zval[(size_t)row * KSP + rank] = ur[idx];
    }
}

// ---------------------------------------------------------------------------
__global__ __launch_bounds__(256) void zfill_scatter_kernel(const int* __restrict__ zidx,
                                                            const float* __restrict__ zval,
                                                            float* __restrict__ zden)
{
    const int t  = threadIdx.x;
    const int r0 = blockIdx.x * 8;
    float* base = zden + (size_t)r0 * CODE_DIM;
    const float4 zero = make_float4(0.f, 0.f, 0.f, 0.f);
    for (int q = t; q < 8 * CODE_DIM / 4; q += 256)
        *(float4*)&base[q * 4] = zero;
    __syncthreads();
    const int rl = t >> 5, k = t & 31;
    int   idx = zidx[(size_t)(r0 + rl) * KSP + k];
    float v   = zval[(size_t)(r0 + rl) * KSP + k];
    base[(size_t)rl * CODE_DIM + idx] = v;
}

// ---------------------------------------------------------------------------
// recon: ascending-index fold of 32 nonzeros, f32 fmaf (np z@D.T faithful)
__global__ __launch_bounds__(128) void recon_kernel(const int* __restrict__ zidx,
                                                    const float* __restrict__ zval,
                                                    const float* __restrict__ Dt,
                                                    float* __restrict__ recon)
{
    const int t   = threadIdx.x;
    const int row = blockIdx.x;
    float4 acc = make_float4(0.f, 0.f, 0.f, 0.f);
    const int*   ip = zidx + (size_t)row * KSP;
    const float* vp = zval + (size_t)row * KSP;
    for (int k = 0; k < KSP; ++k) {
        int   j = ip[k];
        float v = vp[k];
        float4 d = *(const float4*)&Dt[(size_t)j * INPUT_DIM + t * 4];
        acc.x = fmaf(v, d.x, acc.x);
        acc.y = fmaf(v, d.y, acc.y);
        acc.z = fmaf(v, d.z, acc.z);
        acc.w = fmaf(v, d.w, acc.w);
    }
    *(float4*)&recon[(size_t)row * INPUT_DIM + t * 4] = acc;
}

// ---------------------------------------------------------------------------
extern "C" void kernel_launch(void* const* d_in, const int* in_sizes, int n_in,
                              void* d_out, int out_size, void* d_ws, size_t ws_size,
                              hipStream_t stream)
{
    const float* x = (const float*)d_in[0];
    const float* W = (const float*)d_in[1];   // [5][512][2048]
    const float* S = (const float*)d_in[2];   // [5][2048][2048]
    const float* D = (const float*)d_in[3];   // [512][2048]

    float* recon = (float*)d_out;
    float* zden  = (float*)d_out + (size_t)BATCH * INPUT_DIM;  // u scratch, then dense z

    int*   zidx = (int*)d_ws;
    float* zval = (float*)((char*)d_ws + (size_t)BATCH * KSP * 4);
    float* Dt   = (float*)((char*)d_ws + (size_t)2 * BATCH * KSP * 4);

    transpose_512x2048_kernel<<<dim3(CODE_DIM / 32, INPUT_DIM / 32), dim3(32, 8), 0, stream>>>(D, Dt);

    for (int l = 0; l < LAYERS; ++l) {
        const float* Wl = W + (size_t)l * INPUT_DIM * CODE_DIM;
        const float* Sl = (l == 0) ? nullptr : S + (size_t)l * CODE_DIM * CODE_DIM;
        gemm_layer_kernel<<<dim3(CODE_DIM / BN, BATCH / BM), 256, 0, stream>>>(
            x, Wl, Sl, (l == 0) ? nullptr : zidx, (l == 0) ? nullptr : zval, zden);
        topk32_wave_kernel<<<BATCH / 4, 256, 0, stream>>>(zden, zidx, zval);
    }

    zfill_scatter_kernel<<<BATCH / 8, 256, 0, stream>>>(zidx, zval, zden);
    recon_kernel<<<BATCH, 128, 0, stream>>>(zidx, zval, Dt, recon);
}